// Round 3
// baseline (307.277 us; speedup 1.0000x reference)
//
#include <hip/hip_runtime.h>

#define HH 256
#define WW 256
#define NPIX (2 * HH * WW)   // 131072 (B=2)
#define NC 48
#define NB 31
#define NG 6          // channel groups
#define CG 8          // channels per group (NG*CG == NC)
#define OT 32         // output tile (32x32 per block)
#define PT 38         // phi tile = OT+6
#define PSTR 40       // phi LDS row stride (16B-aligned rows)
#define UT 44         // u tile = OT+12
#define USTR 48       // u LDS row stride (16B-aligned rows)
#define TM 385        // phi-table points per channel, x in [-1.5,1.5], h=3/384

// ---- Build per-channel phi tables: phi_c(x) = sum_k w[c,k] exp(-50 (x-mu_k)^2)
// 48 blocks, one per channel. Output: (value, delta) float2 pairs for lerp.
__global__ __launch_bounds__(256)
void tnrd_table(const float* __restrict__ wr, float2* __restrict__ tab)
{
    const int ch = blockIdx.x;
    __shared__ float val[TM + 1];
    for (int idx = threadIdx.x; idx < TM + 1; idx += 256) {
        float x = -1.5f + (float)idx * (3.0f / 384.0f);
        float s = 0.f;
        #pragma unroll
        for (int k = 0; k < NB; ++k) {
            float mu = -1.f + (float)k * (1.f / 15.f);
            float d = x - mu;
            s = fmaf(wr[ch * NB + k], __expf(-50.f * d * d), s);
        }
        val[idx] = s;
    }
    __syncthreads();
    for (int idx = threadIdx.x; idx < TM; idx += 256)
        tab[ch * TM + idx] = make_float2(val[idx], val[idx + 1] - val[idx]);
}

// ---- Fused: conv1(7x7, 8 ch at once) -> table-lerp RBF -> conv2(flipped 7x7)
__global__ __launch_bounds__(256, 3)
void tnrd_main(const float* __restrict__ u,
               const float* __restrict__ wf,     // filters [48][49]
               const float2* __restrict__ tab,   // [48][TM] (value, delta)
               float* __restrict__ part)
{
    __shared__ __align__(16) float u_s[UT * USTR];
    __shared__ __align__(16) float phi_s[2][PT * PSTR];
    __shared__ __align__(16) float2 tabs[CG][TM];

    const int tid = threadIdx.x;
    const int bx = blockIdx.x, by = blockIdx.y;
    const int b = blockIdx.z / NG, g = blockIdx.z % NG;
    const int c0 = g * CG;

    // ---- stage u tile (6-halo, zero-padded incl. stride pad) ----
    const int uy0 = by * OT - 6, ux0 = bx * OT - 6;
    const float* ub = u + b * (HH * WW);
    for (int i = tid; i < UT * USTR; i += 256) {
        int r = i / USTR, c = i - r * USTR;
        int gy = uy0 + r, gx = ux0 + c;
        float v = 0.f;
        if (c < UT && (unsigned)gy < HH && (unsigned)gx < WW)
            v = ub[gy * WW + gx];
        u_s[i] = v;
    }
    // ---- stage this group's 8 phi tables (L2-resident source) ----
    {
        const float4* tsrc = (const float4*)(tab + c0 * TM);
        float4* tdst = (float4*)&tabs[0][0];
        for (int i = tid; i < CG * TM / 2; i += 256) tdst[i] = tsrc[i];
    }
    __syncthreads();

    // ---- conv1: all 8 channels per u_s read; 4 adjacent px per item ----
    const bool has2 = (tid + 256) < PT * 10;   // 380 items total
    float cv[2][CG][4];
    int prA[2], pcA[2];
    #pragma unroll
    for (int p = 0; p < 2; ++p) {
        if (p == 0 || has2) {
            const int gi = tid + p * 256;
            const int pr = gi / 10, pc = (gi - pr * 10) * 4;
            prA[p] = pr; pcA[p] = pc;
            #pragma unroll
            for (int ch = 0; ch < CG; ++ch)
                #pragma unroll
                for (int j = 0; j < 4; ++j) cv[p][ch][j] = 0.f;
            for (int dy = 0; dy < 7; ++dy) {        // not unrolled: code size
                const float* row = &u_s[(pr + dy) * USTR + pc];
                float sv[12];
                #pragma unroll
                for (int j = 0; j < 12; ++j) sv[j] = row[j];  // 3x ds_read_b128
                #pragma unroll
                for (int ch = 0; ch < CG; ++ch) {
                    const float* wc = wf + (c0 + ch) * 49 + dy * 7;  // s_load
                    #pragma unroll
                    for (int dx = 0; dx < 7; ++dx) {
                        float w = wc[dx];
                        cv[p][ch][0] = fmaf(sv[dx],     w, cv[p][ch][0]);
                        cv[p][ch][1] = fmaf(sv[dx + 1], w, cv[p][ch][1]);
                        cv[p][ch][2] = fmaf(sv[dx + 2], w, cv[p][ch][2]);
                        cv[p][ch][3] = fmaf(sv[dx + 3], w, cv[p][ch][3]);
                    }
                }
            }
        }
    }

    const int oy = tid >> 3;        // 0..31
    const int ox0 = (tid & 7) * 4;  // 0..28
    float o0 = 0.f, o1 = 0.f, o2 = 0.f, o3 = 0.f;
    const int py0 = by * OT - 3, px0 = bx * OT - 3;

    #pragma unroll
    for (int ci = 0; ci < CG; ++ci) {
        float* pb = &phi_s[ci & 1][0];

        // ---- RBF via table lerp; mask phi to 0 outside the image ----
        #pragma unroll
        for (int p = 0; p < 2; ++p) {
            if (p == 0 || has2) {
                const int pr = prA[p], pc = pcA[p];
                const int gy = py0 + pr;
                const bool rowok = (unsigned)gy < HH;
                float ph[4];
                #pragma unroll
                for (int j = 0; j < 4; ++j) {
                    float x = cv[p][ci][j];
                    float t = fminf(fmaxf(fmaf(x, 128.f, 192.f), 0.f), 383.999f);
                    float fj = floorf(t);
                    float fr = t - fj;
                    float2 e = tabs[ci][(int)fj];          // ds_read_b64 gather
                    float v = fmaf(fr, e.y, e.x);
                    int gx = px0 + pc + j;
                    ph[j] = (rowok && (unsigned)gx < WW) ? v : 0.f;
                }
                float* dst = &pb[pr * PSTR + pc];
                #pragma unroll
                for (int j = 0; j < 4; ++j) dst[j] = ph[j]; // ds_write_b128
            }
        }
        __syncthreads();
        // double-buffered phi: next channel writes the other buffer; its
        // barrier orders those writes after this channel's conv2 reads.

        // ---- conv2 accumulate, spatially-flipped weights ----
        const float* wc2 = wf + (c0 + ci) * 49;
        for (int dy = 0; dy < 7; ++dy) {            // not unrolled: code size
            const float* prow = &pb[(oy + dy) * PSTR + ox0];
            float sv[10];
            #pragma unroll
            for (int j = 0; j < 10; ++j) sv[j] = prow[j];
            #pragma unroll
            for (int dx = 0; dx < 7; ++dx) {
                float w = wc2[(6 - dy) * 7 + (6 - dx)];
                o0 = fmaf(sv[dx],     w, o0);
                o1 = fmaf(sv[dx + 1], w, o1);
                o2 = fmaf(sv[dx + 2], w, o2);
                o3 = fmaf(sv[dx + 3], w, o3);
            }
        }
    }

    const int gy = by * OT + oy, gx = bx * OT + ox0;
    float4 v4 = make_float4(o0, o1, o2, o3);
    *reinterpret_cast<float4*>(part + (size_t)g * NPIX + b * (HH * WW)
                               + gy * WW + gx) = v4;
}

__global__ __launch_bounds__(256)
void combine_kernel(const float* __restrict__ u,
                    const float* __restrict__ f,
                    const float* __restrict__ lam,
                    const float* __restrict__ part,
                    float* __restrict__ out)
{
    int i = blockIdx.x * 256 + threadIdx.x;  // 512 blocks -> NPIX
    float d = 0.f;
    #pragma unroll
    for (int g = 0; g < NG; ++g) d += part[g * NPIX + i];
    float lv = lam[0];
    float uv = u[i];
    float fv = f[i];
    out[i] = uv - d - lv * (uv - fv);
}

extern "C" void kernel_launch(void* const* d_in, const int* in_sizes, int n_in,
                              void* d_out, int out_size, void* d_ws, size_t ws_size,
                              hipStream_t stream) {
    const float* u    = (const float*)d_in[0];
    const float* f    = (const float*)d_in[1];
    const float* filt = (const float*)d_in[2];
    const float* rbfw = (const float*)d_in[3];
    const float* lam  = (const float*)d_in[4];
    float* out = (float*)d_out;
    float* part = (float*)d_ws;           // 6 * 131072 f32 (3 MB)
    // phi tables overlaid on d_out scratch (36,960 floats <= 131,072);
    // combine_kernel fully overwrites d_out afterwards.
    float2* tabg = (float2*)d_out;

    tnrd_table<<<NC, 256, 0, stream>>>(rbfw, tabg);
    tnrd_main<<<dim3(8, 8, 2 * NG), 256, 0, stream>>>(u, filt, (const float2*)tabg, part);
    combine_kernel<<<512, 256, 0, stream>>>(u, f, lam, part, out);
}

// Round 4
// 118.895 us; speedup vs baseline: 2.5844x; 2.5844x over previous
//
#include <hip/hip_runtime.h>

#define HH 256
#define WW 256
#define NPIX (2 * HH * WW)   // 131072 (B=2)
#define NC 48
#define NB 31
#define NG 6          // channel groups
#define CG 8          // channels per group (NG*CG == NC)
#define OT 32         // output tile (32x32 per block)
#define PT 38         // phi tile = OT+6
#define PSTR 44       // phi LDS row stride (16B aligned; 44%32=12 spreads banks)
#define UT 44         // u tile = OT+12
#define USTR 52       // u LDS row stride (16B aligned; 52%32=20 spreads banks)
#define TM 385        // phi-table points per channel, x in [-1.5,1.5], h=3/384

// Fused: per-block phi tables -> conv1(7x7, 2ch/pass) -> table-lerp RBF ->
// conv2(flipped 7x7). All f32. Weights via block-uniform s_load (L2-resident).
// NOTE: all per-lane accumulators are NAMED SCALARS — round 3's cv[2][8][4]
// array was demoted to scratch (700 MB of HBM spill traffic, 2x regression).
__global__ __launch_bounds__(256, 3)
void tnrd_main(const float* __restrict__ u,
               const float* __restrict__ wf,   // filters [48][49]
               const float* __restrict__ wr,   // rbf weights [48][31]
               float* __restrict__ part)
{
    __shared__ __align__(16) float u_s[UT * USTR];          //  9152 B
    __shared__ __align__(16) float phi_s[2][PT * PSTR];     // 13376 B
    __shared__ __align__(16) float tabs[CG][TM + 1];        // 12352 B

    const int tid = threadIdx.x;
    const int bx = blockIdx.x, by = blockIdx.y;
    const int b = blockIdx.z / NG, g = blockIdx.z % NG;
    const int c0 = g * CG;

    // ---- stage u tile (6-halo, zero-padded incl. stride pad) ----
    const int uy0 = by * OT - 6, ux0 = bx * OT - 6;
    const float* ub = u + b * (HH * WW);
    for (int i = tid; i < UT * USTR; i += 256) {
        int r = i / USTR, c = i - r * USTR;
        int gy = uy0 + r, gx = ux0 + c;
        float v = 0.f;
        if (c < UT && (unsigned)gy < HH && (unsigned)gx < WW)
            v = ub[gy * WW + gx];
        u_s[i] = v;
    }

    // ---- build this group's 8 phi tables in LDS (386 pts incl. lerp guard) ----
    #pragma unroll
    for (int ch = 0; ch < CG; ++ch) {
        const float* rc = wr + (c0 + ch) * NB;   // block-uniform -> s_load
        for (int j = tid; j < TM + 1; j += 256) {
            float x = fmaf((float)j, 3.0f / 384.0f, -1.5f);
            float s = 0.f;
            #pragma unroll
            for (int k = 0; k < NB; ++k) {
                float mu = -1.f + (float)k * (1.f / 15.f);
                float d = x - mu;
                s = fmaf(rc[k], __expf(-50.f * d * d), s);
            }
            tabs[ch][j] = s;
        }
    }
    __syncthreads();

    const int oy = tid >> 3;        // 0..31
    const int ox0 = (tid & 7) * 4;  // 0..28
    float o0 = 0.f, o1 = 0.f, o2 = 0.f, o3 = 0.f;
    const int py0 = by * OT - 3, px0 = bx * OT - 3;

    for (int pass = 0; pass < 4; ++pass) {       // 2 channels per pass
        const int ca = c0 + 2 * pass;
        const float* wA = wf + ca * 49;          // block-uniform -> s_load
        const float* wB = wA + 49;

        // ---- conv1 + RBF lerp for both channels; items processed serially ----
        for (int p = 0; p < 2; ++p) {
            const int gi = tid + p * 256;
            if (gi < PT * 10) {                  // 380 items: 38 rows x 10 quads
                const int pr = gi / 10, pc = (gi - pr * 10) * 4;
                float a0 = 0.f, a1 = 0.f, a2 = 0.f, a3 = 0.f;   // ch A, 4 px
                float b0 = 0.f, b1 = 0.f, b2 = 0.f, b3 = 0.f;   // ch B, 4 px
                for (int dy = 0; dy < 7; ++dy) {
                    const float* row = &u_s[(pr + dy) * USTR + pc];
                    float sv[12];
                    #pragma unroll
                    for (int j = 0; j < 12; ++j) sv[j] = row[j]; // 3x ds_read_b128
                    const float* wa = wA + dy * 7;
                    const float* wb = wB + dy * 7;
                    #pragma unroll
                    for (int dx = 0; dx < 7; ++dx) {
                        float fa = wa[dx], fb = wb[dx];
                        a0 = fmaf(sv[dx],     fa, a0);
                        a1 = fmaf(sv[dx + 1], fa, a1);
                        a2 = fmaf(sv[dx + 2], fa, a2);
                        a3 = fmaf(sv[dx + 3], fa, a3);
                        b0 = fmaf(sv[dx],     fb, b0);
                        b1 = fmaf(sv[dx + 1], fb, b1);
                        b2 = fmaf(sv[dx + 2], fb, b2);
                        b3 = fmaf(sv[dx + 3], fb, b3);
                    }
                }
                // ---- table lerp; phi = 0 outside image (conv2 zero-pad) ----
                const int gy = py0 + pr;
                const bool rowok = (unsigned)gy < HH;
                float av[4] = {a0, a1, a2, a3};
                float bv[4] = {b0, b1, b2, b3};
                float pha[4], phb[4];
                #pragma unroll
                for (int j = 0; j < 4; ++j) {
                    bool ok = rowok && (unsigned)(px0 + pc + j) < WW;
                    float ta = fminf(fmaxf(fmaf(av[j], 128.f, 192.f), 0.f), 383.999f);
                    float fja = floorf(ta);
                    float e0a = tabs[2 * 0 + 0][0]; // placeholder to keep shape
                    (void)e0a;
                    int ia = (int)fja;
                    float va = fmaf(ta - fja, tabs[2*pass][ia+1] - tabs[2*pass][ia],
                                    tabs[2*pass][ia]);
                    float tb = fminf(fmaxf(fmaf(bv[j], 128.f, 192.f), 0.f), 383.999f);
                    float fjb = floorf(tb);
                    int ib = (int)fjb;
                    float vb = fmaf(tb - fjb, tabs[2*pass+1][ib+1] - tabs[2*pass+1][ib],
                                    tabs[2*pass+1][ib]);
                    pha[j] = ok ? va : 0.f;
                    phb[j] = ok ? vb : 0.f;
                }
                float* dA = &phi_s[0][pr * PSTR + pc];
                float* dB = &phi_s[1][pr * PSTR + pc];
                #pragma unroll
                for (int j = 0; j < 4; ++j) dA[j] = pha[j];  // ds_write_b128
                #pragma unroll
                for (int j = 0; j < 4; ++j) dB[j] = phb[j];  // ds_write_b128
            }
        }
        __syncthreads();

        // ---- conv2 accumulate both channels, spatially-flipped weights ----
        for (int dy = 0; dy < 7; ++dy) {
            const float* rA = &phi_s[0][(oy + dy) * PSTR + ox0];
            const float* rB = &phi_s[1][(oy + dy) * PSTR + ox0];
            float sa[10], sb[10];
            #pragma unroll
            for (int j = 0; j < 10; ++j) sa[j] = rA[j];
            #pragma unroll
            for (int j = 0; j < 10; ++j) sb[j] = rB[j];
            #pragma unroll
            for (int dx = 0; dx < 7; ++dx) {
                float fa = wA[(6 - dy) * 7 + (6 - dx)];
                float fb = wB[(6 - dy) * 7 + (6 - dx)];
                o0 = fmaf(sa[dx],     fa, o0);
                o1 = fmaf(sa[dx + 1], fa, o1);
                o2 = fmaf(sa[dx + 2], fa, o2);
                o3 = fmaf(sa[dx + 3], fa, o3);
                o0 = fmaf(sb[dx],     fb, o0);
                o1 = fmaf(sb[dx + 1], fb, o1);
                o2 = fmaf(sb[dx + 2], fb, o2);
                o3 = fmaf(sb[dx + 3], fb, o3);
            }
        }
        __syncthreads();   // protect phi_s before next pass overwrites
    }

    const int gy = by * OT + oy, gx = bx * OT + ox0;
    float4 v4 = make_float4(o0, o1, o2, o3);
    *reinterpret_cast<float4*>(part + (size_t)g * NPIX + b * (HH * WW)
                               + gy * WW + gx) = v4;
}

__global__ __launch_bounds__(256)
void combine_kernel(const float* __restrict__ u,
                    const float* __restrict__ f,
                    const float* __restrict__ lam,
                    const float* __restrict__ part,
                    float* __restrict__ out)
{
    int i = blockIdx.x * 256 + threadIdx.x;  // 512 blocks -> NPIX
    float d = 0.f;
    #pragma unroll
    for (int g = 0; g < NG; ++g) d += part[g * NPIX + i];
    float lv = lam[0];
    float uv = u[i];
    float fv = f[i];
    out[i] = uv - d - lv * (uv - fv);
}

extern "C" void kernel_launch(void* const* d_in, const int* in_sizes, int n_in,
                              void* d_out, int out_size, void* d_ws, size_t ws_size,
                              hipStream_t stream) {
    const float* u    = (const float*)d_in[0];
    const float* f    = (const float*)d_in[1];
    const float* filt = (const float*)d_in[2];
    const float* rbfw = (const float*)d_in[3];
    const float* lam  = (const float*)d_in[4];
    float* out = (float*)d_out;
    float* part = (float*)d_ws;   // 6 * 131072 f32 partial sums (3 MB)

    tnrd_main<<<dim3(8, 8, 2 * NG), 256, 0, stream>>>(u, filt, rbfw, part);
    combine_kernel<<<512, 256, 0, stream>>>(u, f, lam, part, out);
}